// Round 3
// baseline (79.274 us; speedup 1.0000x reference)
//
#include <hip/hip_runtime.h>
#include <cstddef>

#define Bn 16
#define Dn 512
#define Tn 2048
#define Ln 512

__constant__ float kSigmaSq = 5.0f;

// ---------------- K1: score[b,t] = exp(x[b,:,t].w) * mask ----------------
// 512 blocks (b, 64-t chunk), 256 thr; float4 loads along t.
__global__ __launch_bounds__(256) void score_kernel(const float* __restrict__ x,
                                                    const float* __restrict__ w,
                                                    const int* __restrict__ xlen,
                                                    float* __restrict__ score) {
    int blk = blockIdx.x;
    int b   = blk >> 5;
    int tc  = blk & 31;
    int tid = threadIdx.x;
    int tq  = tid & 15;          // 16 float4 slots = 64 t
    int dg  = tid >> 4;          // 16 d-groups of 32
    int t0  = tc * 64 + tq * 4;
    const float* xb = x + (size_t)b * Dn * Tn + t0;
    float4 acc = make_float4(0.f, 0.f, 0.f, 0.f);
    int dbase = dg * 32;
#pragma unroll 8
    for (int i = 0; i < 32; ++i) {
        int d = dbase + i;
        float4 v = *(const float4*)&xb[(size_t)d * Tn];
        float wd = w[d];
        acc.x = fmaf(v.x, wd, acc.x);
        acc.y = fmaf(v.y, wd, acc.y);
        acc.z = fmaf(v.z, wd, acc.z);
        acc.w = fmaf(v.w, wd, acc.w);
    }
    __shared__ float4 red[16][16];
    red[dg][tq] = acc;
    __syncthreads();
    if (tid < 16) {
        float4 s = red[0][tid];
#pragma unroll
        for (int g = 1; g < 16; ++g) {
            float4 r = red[g][tid];
            s.x += r.x; s.y += r.y; s.z += r.z; s.w += r.w;
        }
        int xl = xlen[b];
        int t  = tc * 64 + tid * 4;
        float4 o;
        o.x = (t + 0 < xl) ? __expf(s.x) : 0.f;
        o.y = (t + 1 < xl) ? __expf(s.y) : 0.f;
        o.z = (t + 2 < xl) ? __expf(s.z) : 0.f;
        o.w = (t + 3 < xl) ? __expf(s.w) : 0.f;
        *(float4*)&score[b * Tn + t] = o;
    }
}

// ---------------- K2: per-b scan -> norm, loss partial, z_mask, z_len ----
__global__ __launch_bounds__(256) void scan_kernel(const float* __restrict__ score,
                                                   const int* __restrict__ xlen,
                                                   float* __restrict__ norm,
                                                   float* __restrict__ loss_part,
                                                   float* __restrict__ zmask_out,
                                                   float* __restrict__ zlen_out) {
    int b = blockIdx.x, tid = threadIdx.x;
    int xl = xlen[b];
    int zl = (xl + 3) >> 2;
    const float* sc = score + b * Tn;

    float v[8]; float s = 0.f;
#pragma unroll
    for (int k = 0; k < 8; ++k) { v[k] = sc[tid * 8 + k]; s += v[k]; }

    float ps = s;
#pragma unroll
    for (int off = 1; off < 64; off <<= 1) {
        float n = __shfl_up(ps, off, 64);
        if ((tid & 63) >= off) ps += n;
    }
    __shared__ float wsum[4];
    if ((tid & 63) == 63) wsum[tid >> 6] = ps;
    __syncthreads();
    float base = 0.f;
#pragma unroll
    for (int wv = 0; wv < 4; ++wv) if (wv < (tid >> 6)) base += wsum[wv];
    float total = wsum[0] + wsum[1] + wsum[2] + wsum[3];
    float cum0  = sc[0];
    float scale = (float)(zl - 1) / (total - cum0);

    float run = base + ps - s;
#pragma unroll
    for (int k = 0; k < 8; ++k) {
        run += v[k];
        norm[b * Tn + tid * 8 + k] = (run - cum0) * scale;
    }

    float ls = 0.f;
#pragma unroll
    for (int k = 0; k < 8; ++k) {
        int t = tid * 8 + k;
        if (t >= 1 && t < xl) {
            float diff = v[k] * scale;
            ls += fmaxf(diff - 1.0f, 0.f);
        }
    }
#pragma unroll
    for (int off = 32; off; off >>= 1) ls += __shfl_down(ls, off, 64);
    __shared__ float lw[4];
    if ((tid & 63) == 0) lw[tid >> 6] = ls;
    __syncthreads();
    if (tid == 0) loss_part[b] = (lw[0] + lw[1] + lw[2] + lw[3]) / (float)(xl - 1);

    for (int l = tid; l < Ln; l += 256)
        zmask_out[b * Ln + l] = (l * 4 < xl) ? 1.f : 0.f;
    if (tid == 0) zlen_out[b] = (float)zl;
}

__global__ void loss_kernel(const float* __restrict__ loss_part, float* __restrict__ out_loss) {
    if (threadIdx.x == 0) {
        float s = 0.f;
        for (int i = 0; i < Bn; ++i) s += loss_part[i];
        out_loss[0] = s / (float)Bn;
    }
}

// ---------------- K3: alignment[b,l,:] = softmax_t(-5(l-norm)^2) ---------
__global__ __launch_bounds__(256) void softmax_kernel(const float* __restrict__ norm,
                                                      const int* __restrict__ xlen,
                                                      float* __restrict__ align) {
    int bl  = blockIdx.x;
    int b   = bl >> 9;
    int l   = bl & (Ln - 1);
    int tid = threadIdx.x;
    int xl  = xlen[b];
    int zl  = (xl + 3) >> 2;
    float* arow = align + (size_t)bl * Tn;
    if (l >= zl) {
#pragma unroll
        for (int k = 0; k < 8; ++k) arow[tid + k * 256] = 0.f;
        return;
    }
    const float* nb = norm + b * Tn;
    float dv[8], mx = -1e30f;
#pragma unroll
    for (int k = 0; k < 8; ++k) {
        int t = tid + k * 256;
        float df = (float)l - nb[t];
        float dd = -kSigmaSq * df * df;
        dv[k] = (t < xl) ? dd : -1e30f;
        mx = fmaxf(mx, dv[k]);
    }
#pragma unroll
    for (int off = 32; off; off >>= 1) mx = fmaxf(mx, __shfl_xor(mx, off, 64));
    __shared__ float sr1[4], sr2[4];
    if ((tid & 63) == 0) sr1[tid >> 6] = mx;
    __syncthreads();
    mx = fmaxf(fmaxf(sr1[0], sr1[1]), fmaxf(sr1[2], sr1[3]));
    float e[8], sum = 0.f;
#pragma unroll
    for (int k = 0; k < 8; ++k) { e[k] = __expf(dv[k] - mx); sum += e[k]; }
#pragma unroll
    for (int off = 32; off; off >>= 1) sum += __shfl_xor(sum, off, 64);
    if ((tid & 63) == 0) sr2[tid >> 6] = sum;
    __syncthreads();
    sum = sr2[0] + sr2[1] + sr2[2] + sr2[3];
    float inv = 1.0f / sum;
#pragma unroll
    for (int k = 0; k < 8; ++k) arow[tid + k * 256] = e[k] * inv;
}

// ---------------- K4: z[b,d,l] = sum_t align[b,l,t]*x[b,d,t] (windowed) --
__device__ __forceinline__ int lb_ge(const float* a, int n, float v) {
    int lo = 0, hi = n;
    while (lo < hi) { int m = (lo + hi) >> 1; if (a[m] < v) lo = m + 1; else hi = m; }
    return lo;
}
__device__ __forceinline__ int ub_gt(const float* a, int n, float v) {
    int lo = 0, hi = n;
    while (lo < hi) { int m = (lo + hi) >> 1; if (a[m] <= v) lo = m + 1; else hi = m; }
    return lo;
}

#define ZD 256
#define ZL 8
#define ZT 8

// Single-wave blocks (64 thr), 256d x 8l tile, TC=8, double-buffered, no barriers.
// Grid 2048 = Bn*2*64; per-thread 8d x 4l registers.
__global__ __launch_bounds__(64, 2) void zgemm3_kernel(const float* __restrict__ x,
                                                       const float* __restrict__ align,
                                                       const float* __restrict__ norm,
                                                       const int* __restrict__ xlen,
                                                       float* __restrict__ z) {
    // bijective XCD swizzle (2048 % 8 == 0): each XCD gets 2 consecutive b's
    int wg  = blockIdx.x;
    int swz = (wg & 7) * 256 + (wg >> 3);
    int b   = swz >> 7;
    int dh  = (swz >> 6) & 1;
    int lt  = swz & 63;
    int l0  = lt * ZL, d0 = dh * ZD;
    int xl  = xlen[b];
    const float* nb = norm + b * Tn;

    int t_lo = lb_ge(nb, Tn, (float)l0 - 2.0f) & ~(ZT - 1);
    int t_hi = ub_gt(nb, Tn, (float)(l0 + ZL - 1) + 2.0f);
    if (t_hi > xl) t_hi = xl;
    int ntiles = (t_hi > t_lo) ? ((t_hi - t_lo + ZT - 1) >> 3) : 0;

    __shared__ float sX[2][ZT][ZD];   // 16 KB, t-major
    __shared__ float sA[2][ZT][ZL];   // 512 B

    int tid = threadIdx.x;
    int tl  = tid & 7;     // staging: t within tile
    int dq  = tid >> 3;    // staging: d-quad group (0..7), quads dq + 8i
    int dg  = tid & 31;    // compute: d = 4dg / 128+4dg
    int lg  = tid >> 5;    // compute: l = 4lg

    const float* xp = x + (size_t)(b * Dn + d0 + 4 * dq) * Tn;
    const float* ap = align + (size_t)(b * Ln + l0 + dq) * Tn;

    float4 rx[8];
    float  ra;
    float  acc[8][4] = {};

#define STAGE_LOAD(IT)                                                         \
    {                                                                          \
        int t  = t_lo + (IT) * ZT + tl;                                        \
        int tc = (t < Tn - 1) ? t : Tn - 1;                                    \
        _Pragma("unroll")                                                      \
        for (int i = 0; i < 8; ++i) {                                          \
            size_t o = (size_t)(32 * i) * Tn + tc;                             \
            rx[i].x = xp[o];                                                   \
            rx[i].y = xp[o + Tn];                                              \
            rx[i].z = xp[o + 2 * Tn];                                          \
            rx[i].w = xp[o + 3 * Tn];                                          \
        }                                                                      \
        ra = (t < t_hi) ? ap[tc] : 0.f;                                        \
    }
#define STAGE_WRITE(BUF)                                                       \
    {                                                                          \
        _Pragma("unroll")                                                      \
        for (int i = 0; i < 8; ++i)                                            \
            *(float4*)&sX[BUF][tl][4 * dq + 32 * i] = rx[i];                   \
        sA[BUF][tl][dq] = ra;                                                  \
    }

    if (ntiles > 0) { STAGE_LOAD(0); STAGE_WRITE(0); }

    for (int it = 0; it < ntiles; ++it) {
        int buf = it & 1;
        if (it + 1 < ntiles) STAGE_LOAD(it + 1);
#pragma unroll
        for (int t = 0; t < ZT; ++t) {
            float4 xa = *(const float4*)&sX[buf][t][4 * dg];
            float4 xc = *(const float4*)&sX[buf][t][128 + 4 * dg];
            float4 av = *(const float4*)&sA[buf][t][4 * lg];
            float xv[8] = {xa.x, xa.y, xa.z, xa.w, xc.x, xc.y, xc.z, xc.w};
            float aw[4] = {av.x, av.y, av.z, av.w};
#pragma unroll
            for (int i = 0; i < 8; ++i)
#pragma unroll
                for (int j = 0; j < 4; ++j)
                    acc[i][j] = fmaf(xv[i], aw[j], acc[i][j]);
        }
        if (it + 1 < ntiles) STAGE_WRITE(buf ^ 1);
    }

#pragma unroll
    for (int i = 0; i < 8; ++i) {
        int d = d0 + (i < 4 ? 4 * dg + i : 128 + 4 * dg + (i - 4));
        float4 vv = make_float4(acc[i][0], acc[i][1], acc[i][2], acc[i][3]);
        *(float4*)&z[(size_t)(b * Dn + d) * Ln + l0 + 4 * lg] = vv;
    }
#undef STAGE_LOAD
#undef STAGE_WRITE
}

extern "C" void kernel_launch(void* const* d_in, const int* in_sizes, int n_in,
                              void* d_out, int out_size, void* d_ws, size_t ws_size,
                              hipStream_t stream) {
    const float* x    = (const float*)d_in[0];
    const float* w    = (const float*)d_in[1];
    const int*   xlen = (const int*)d_in[3];
    float* out = (float*)d_out;

    const size_t OFF_Z     = 0;
    const size_t OFF_ZMASK = (size_t)Bn * Dn * Ln;
    const size_t OFF_ZLEN  = OFF_ZMASK + (size_t)Bn * Ln;
    const size_t OFF_ALIGN = OFF_ZLEN + Bn;
    const size_t OFF_LOSS  = OFF_ALIGN + (size_t)Bn * Ln * Tn;

    float* score     = (float*)d_ws;
    float* norm      = score + (size_t)Bn * Tn;
    float* loss_part = norm + (size_t)Bn * Tn;

    score_kernel<<<Bn * 32, 256, 0, stream>>>(x, w, xlen, score);
    scan_kernel<<<Bn, 256, 0, stream>>>(score, xlen, norm, loss_part,
                                        out + OFF_ZMASK, out + OFF_ZLEN);
    loss_kernel<<<1, 64, 0, stream>>>(loss_part, out + OFF_LOSS);
    softmax_kernel<<<Bn * Ln, 256, 0, stream>>>(norm, xlen, out + OFF_ALIGN);
    zgemm3_kernel<<<Bn * 2 * 64, 64, 0, stream>>>(x, out + OFF_ALIGN, norm, xlen,
                                                  out + OFF_Z);
}

// Round 4
// 66.209 us; speedup vs baseline: 1.1973x; 1.1973x over previous
//
#include <hip/hip_runtime.h>
#include <cstddef>

#define Bn 16
#define Dn 512
#define Tn 2048
#define Ln 512

__constant__ float kSigmaSq = 5.0f;

// ---------------- K1: score[b,t] = exp(x[b,:,t].w) * mask ----------------
__global__ __launch_bounds__(256) void score_kernel(const float* __restrict__ x,
                                                    const float* __restrict__ w,
                                                    const int* __restrict__ xlen,
                                                    float* __restrict__ score) {
    int blk = blockIdx.x;
    int b   = blk >> 5;
    int tc  = blk & 31;
    int tid = threadIdx.x;
    int xl  = xlen[b];
    int t0c = tc * 64;
    if (t0c >= xl) {                     // fully masked chunk: zero, skip loads
        if (tid < 16)
            *(float4*)&score[b * Tn + t0c + tid * 4] = make_float4(0.f, 0.f, 0.f, 0.f);
        return;
    }
    int tq  = tid & 15;
    int dg  = tid >> 4;
    int t0  = t0c + tq * 4;
    const float* xb = x + (size_t)b * Dn * Tn + t0;
    float4 acc = make_float4(0.f, 0.f, 0.f, 0.f);
    int dbase = dg * 32;
#pragma unroll 8
    for (int i = 0; i < 32; ++i) {
        int d = dbase + i;
        float4 v = *(const float4*)&xb[(size_t)d * Tn];
        float wd = w[d];
        acc.x = fmaf(v.x, wd, acc.x);
        acc.y = fmaf(v.y, wd, acc.y);
        acc.z = fmaf(v.z, wd, acc.z);
        acc.w = fmaf(v.w, wd, acc.w);
    }
    __shared__ float4 red[16][16];
    red[dg][tq] = acc;
    __syncthreads();
    if (tid < 16) {
        float4 s = red[0][tid];
#pragma unroll
        for (int g = 1; g < 16; ++g) {
            float4 r = red[g][tid];
            s.x += r.x; s.y += r.y; s.z += r.z; s.w += r.w;
        }
        int t = t0c + tid * 4;
        float4 o;
        o.x = (t + 0 < xl) ? __expf(s.x) : 0.f;
        o.y = (t + 1 < xl) ? __expf(s.y) : 0.f;
        o.z = (t + 2 < xl) ? __expf(s.z) : 0.f;
        o.w = (t + 3 < xl) ? __expf(s.w) : 0.f;
        *(float4*)&score[b * Tn + t] = o;
    }
}

// ---------------- K2: per-b scan -> norm, loss partial, z_mask, z_len ----
__global__ __launch_bounds__(256) void scan_kernel(const float* __restrict__ score,
                                                   const int* __restrict__ xlen,
                                                   float* __restrict__ norm,
                                                   float* __restrict__ loss_part,
                                                   float* __restrict__ zmask_out,
                                                   float* __restrict__ zlen_out) {
    int b = blockIdx.x, tid = threadIdx.x;
    int xl = xlen[b];
    int zl = (xl + 3) >> 2;
    const float* sc = score + b * Tn;

    float v[8]; float s = 0.f;
#pragma unroll
    for (int k = 0; k < 8; ++k) { v[k] = sc[tid * 8 + k]; s += v[k]; }

    float ps = s;
#pragma unroll
    for (int off = 1; off < 64; off <<= 1) {
        float n = __shfl_up(ps, off, 64);
        if ((tid & 63) >= off) ps += n;
    }
    __shared__ float wsum[4];
    if ((tid & 63) == 63) wsum[tid >> 6] = ps;
    __syncthreads();
    float base = 0.f;
#pragma unroll
    for (int wv = 0; wv < 4; ++wv) if (wv < (tid >> 6)) base += wsum[wv];
    float total = wsum[0] + wsum[1] + wsum[2] + wsum[3];
    float cum0  = sc[0];
    float scale = (float)(zl - 1) / (total - cum0);

    float run = base + ps - s;
#pragma unroll
    for (int k = 0; k < 8; ++k) {
        run += v[k];
        norm[b * Tn + tid * 8 + k] = (run - cum0) * scale;
    }

    float ls = 0.f;
#pragma unroll
    for (int k = 0; k < 8; ++k) {
        int t = tid * 8 + k;
        if (t >= 1 && t < xl) {
            float diff = v[k] * scale;
            ls += fmaxf(diff - 1.0f, 0.f);
        }
    }
#pragma unroll
    for (int off = 32; off; off >>= 1) ls += __shfl_down(ls, off, 64);
    __shared__ float lw[4];
    if ((tid & 63) == 0) lw[tid >> 6] = ls;
    __syncthreads();
    if (tid == 0) loss_part[b] = (lw[0] + lw[1] + lw[2] + lw[3]) / (float)(xl - 1);

    for (int l = tid; l < Ln; l += 256)
        zmask_out[b * Ln + l] = (l * 4 < xl) ? 1.f : 0.f;
    if (tid == 0) zlen_out[b] = (float)zl;
}

// ---------------- K3: alignment[b,l,:] = softmax_t(-5(l-norm)^2) ---------
__global__ __launch_bounds__(256) void softmax_kernel(const float* __restrict__ norm,
                                                      const int* __restrict__ xlen,
                                                      float* __restrict__ align) {
    int bl  = blockIdx.x;
    int b   = bl >> 9;
    int l   = bl & (Ln - 1);
    int tid = threadIdx.x;
    int xl  = xlen[b];
    int zl  = (xl + 3) >> 2;
    float* arow = align + (size_t)bl * Tn;
    if (l >= zl) {
        float4 zz = make_float4(0.f, 0.f, 0.f, 0.f);
        *(float4*)&arow[tid * 8]     = zz;
        *(float4*)&arow[tid * 8 + 4] = zz;
        return;
    }
    const float* nb = norm + b * Tn;
    float dv[8], mx = -1e30f;
#pragma unroll
    for (int k = 0; k < 8; ++k) {
        int t = tid * 8 + k;
        float df = (float)l - nb[t];
        float dd = -kSigmaSq * df * df;
        dv[k] = (t < xl) ? dd : -1e30f;
        mx = fmaxf(mx, dv[k]);
    }
#pragma unroll
    for (int off = 32; off; off >>= 1) mx = fmaxf(mx, __shfl_xor(mx, off, 64));
    __shared__ float sr1[4], sr2[4];
    if ((tid & 63) == 0) sr1[tid >> 6] = mx;
    __syncthreads();
    mx = fmaxf(fmaxf(sr1[0], sr1[1]), fmaxf(sr1[2], sr1[3]));
    float e[8], sum = 0.f;
#pragma unroll
    for (int k = 0; k < 8; ++k) { e[k] = __expf(dv[k] - mx); sum += e[k]; }
#pragma unroll
    for (int off = 32; off; off >>= 1) sum += __shfl_xor(sum, off, 64);
    if ((tid & 63) == 0) sr2[tid >> 6] = sum;
    __syncthreads();
    sum = sr2[0] + sr2[1] + sr2[2] + sr2[3];
    float inv = 1.0f / sum;
    float4 o0 = make_float4(e[0] * inv, e[1] * inv, e[2] * inv, e[3] * inv);
    float4 o1 = make_float4(e[4] * inv, e[5] * inv, e[6] * inv, e[7] * inv);
    *(float4*)&arow[tid * 8]     = o0;
    *(float4*)&arow[tid * 8 + 4] = o1;
}

// ---------------- K4: z[b,d,l] = sum_t align[b,l,t]*x[b,d,t] (windowed) --
__device__ __forceinline__ int lb_ge(const float* a, int n, float v) {
    int lo = 0, hi = n;
    while (lo < hi) { int m = (lo + hi) >> 1; if (a[m] < v) lo = m + 1; else hi = m; }
    return lo;
}
__device__ __forceinline__ int ub_gt(const float* a, int n, float v) {
    int lo = 0, hi = n;
    while (lo < hi) { int m = (lo + hi) >> 1; if (a[m] <= v) lo = m + 1; else hi = m; }
    return lo;
}

#define ZD 128
#define ZL 8
#define ZT 8
#define ZMARGIN 1.5f

// Single-wave blocks (64 thr), 128d x 8l tile, TC=8. Grid 4096 = 16 blk/CU.
// Single LDS buffer (same-wave DS ops are in-order -> no barrier needed),
// register double-buffer, XOR-swizzled sX (write <=2-way, read conflict-free).
__global__ __launch_bounds__(64) void zgemm4_kernel(const float* __restrict__ x,
                                                    const float* __restrict__ align,
                                                    const float* __restrict__ norm,
                                                    const int* __restrict__ xlen,
                                                    const float* __restrict__ loss_part,
                                                    float* __restrict__ z,
                                                    float* __restrict__ out_loss) {
    int tid = threadIdx.x;
    if (blockIdx.x == 0 && tid == 0) {      // fold loss finalize in here
        float s = 0.f;
        for (int i = 0; i < Bn; ++i) s += loss_part[i];
        out_loss[0] = s / (float)Bn;
    }
    // bijective XCD swizzle (4096 % 8 == 0): 2 consecutive b per XCD
    int wg  = blockIdx.x;
    int swz = (wg & 7) * 512 + (wg >> 3);
    int b   = swz >> 8;
    int dq4 = (swz >> 6) & 3;               // d quarter
    int lt  = swz & 63;
    int l0  = lt * ZL, d0 = dq4 * ZD;
    int xl  = xlen[b];
    const float* nb = norm + b * Tn;

    int t_lo = lb_ge(nb, Tn, (float)l0 - ZMARGIN) & ~(ZT - 1);
    int t_hi = ub_gt(nb, Tn, (float)(l0 + ZL - 1) + ZMARGIN);
    if (t_hi > xl) t_hi = xl;
    int ntiles = (t_hi > t_lo) ? ((t_hi - t_lo + ZT - 1) >> 3) : 0;

    __shared__ float sX[ZT][ZD];   // 4 KB, t-major, XOR-swizzled quads
    __shared__ float sA[ZT][ZL];

    int tl = tid & 7;      // staging: t within tile
    int dq = tid >> 3;     // staging: d-quad 0..7 (quads dq + 8i, i<4)
    int dg = tid & 31;     // compute: d-quad index 0..31
    int lg = tid >> 5;     // compute: l half

    const float* xp = x + (size_t)(b * Dn + d0 + 4 * dq) * Tn;
    const float* ap = align + (size_t)(b * Ln + l0 + dq) * Tn;

    float4 rx[4];
    float  ra;
    float  acc[4][4] = {};

#define STAGE_LOAD(IT)                                                         \
    {                                                                          \
        int t  = t_lo + (IT) * ZT + tl;                                        \
        int tc = (t < Tn - 1) ? t : Tn - 1;                                    \
        _Pragma("unroll")                                                      \
        for (int i = 0; i < 4; ++i) {                                          \
            size_t o = (size_t)(32 * i) * Tn + tc;                             \
            rx[i].x = xp[o];                                                   \
            rx[i].y = xp[o + Tn];                                              \
            rx[i].z = xp[o + 2 * Tn];                                          \
            rx[i].w = xp[o + 3 * Tn];                                          \
        }                                                                      \
        ra = (t < t_hi) ? ap[tc] : 0.f;                                        \
    }
#define STAGE_WRITE()                                                          \
    {                                                                          \
        _Pragma("unroll")                                                      \
        for (int i = 0; i < 4; ++i)                                            \
            *(float4*)&sX[tl][32 * i + 4 * (dq ^ tl)] = rx[i];                 \
        sA[tl][dq] = ra;                                                       \
    }

    if (ntiles > 0) { STAGE_LOAD(0); STAGE_WRITE(); }

    for (int it = 0; it < ntiles; ++it) {
        if (it + 1 < ntiles) STAGE_LOAD(it + 1);
#pragma unroll
        for (int t = 0; t < ZT; ++t) {
            float4 xa = *(const float4*)&sX[t][32 * (dg >> 3) + 4 * ((dg & 7) ^ t)];
            float4 av = *(const float4*)&sA[t][4 * lg];
            float xv[4] = {xa.x, xa.y, xa.z, xa.w};
            float aw[4] = {av.x, av.y, av.z, av.w};
#pragma unroll
            for (int i = 0; i < 4; ++i)
#pragma unroll
                for (int j = 0; j < 4; ++j)
                    acc[i][j] = fmaf(xv[i], aw[j], acc[i][j]);
        }
        if (it + 1 < ntiles) STAGE_WRITE();   // same-wave DS in-order: safe
    }

#pragma unroll
    for (int i = 0; i < 4; ++i) {
        int d = d0 + 4 * dg + i;
        float4 vv = make_float4(acc[i][0], acc[i][1], acc[i][2], acc[i][3]);
        *(float4*)&z[(size_t)(b * Dn + d) * Ln + l0 + 4 * lg] = vv;
    }
#undef STAGE_LOAD
#undef STAGE_WRITE
}

extern "C" void kernel_launch(void* const* d_in, const int* in_sizes, int n_in,
                              void* d_out, int out_size, void* d_ws, size_t ws_size,
                              hipStream_t stream) {
    const float* x    = (const float*)d_in[0];
    const float* w    = (const float*)d_in[1];
    const int*   xlen = (const int*)d_in[3];
    float* out = (float*)d_out;

    const size_t OFF_Z     = 0;
    const size_t OFF_ZMASK = (size_t)Bn * Dn * Ln;
    const size_t OFF_ZLEN  = OFF_ZMASK + (size_t)Bn * Ln;
    const size_t OFF_ALIGN = OFF_ZLEN + Bn;
    const size_t OFF_LOSS  = OFF_ALIGN + (size_t)Bn * Ln * Tn;

    float* score     = (float*)d_ws;
    float* norm      = score + (size_t)Bn * Tn;
    float* loss_part = norm + (size_t)Bn * Tn;

    score_kernel<<<Bn * 32, 256, 0, stream>>>(x, w, xlen, score);
    scan_kernel<<<Bn, 256, 0, stream>>>(score, xlen, norm, loss_part,
                                        out + OFF_ZMASK, out + OFF_ZLEN);
    softmax_kernel<<<Bn * Ln, 256, 0, stream>>>(norm, xlen, out + OFF_ALIGN);
    zgemm4_kernel<<<Bn * 4 * 64, 64, 0, stream>>>(x, out + OFF_ALIGN, norm, xlen,
                                                  loss_part, out + OFF_Z, out + OFF_LOSS);
}

// Round 5
// 63.014 us; speedup vs baseline: 1.2580x; 1.0507x over previous
//
#include <hip/hip_runtime.h>
#include <cstddef>

#define Bn 16
#define Dn 512
#define Tn 2048
#define Ln 512

__constant__ float kSigmaSq = 5.0f;

// ---------------- K1: score[b,t] = exp(x[b,:,t].w) * mask ----------------
__global__ __launch_bounds__(256) void score_kernel(const float* __restrict__ x,
                                                    const float* __restrict__ w,
                                                    const int* __restrict__ xlen,
                                                    float* __restrict__ score) {
    int blk = blockIdx.x;
    int b   = blk >> 5;
    int tc  = blk & 31;
    int tid = threadIdx.x;
    int xl  = xlen[b];
    int t0c = tc * 64;
    if (t0c >= xl) {
        if (tid < 16)
            *(float4*)&score[b * Tn + t0c + tid * 4] = make_float4(0.f, 0.f, 0.f, 0.f);
        return;
    }
    int tq  = tid & 15;
    int dg  = tid >> 4;
    int t0  = t0c + tq * 4;
    const float* xb = x + (size_t)b * Dn * Tn + t0;
    float4 acc = make_float4(0.f, 0.f, 0.f, 0.f);
    int dbase = dg * 32;
#pragma unroll 8
    for (int i = 0; i < 32; ++i) {
        int d = dbase + i;
        float4 v = *(const float4*)&xb[(size_t)d * Tn];
        float wd = w[d];
        acc.x = fmaf(v.x, wd, acc.x);
        acc.y = fmaf(v.y, wd, acc.y);
        acc.z = fmaf(v.z, wd, acc.z);
        acc.w = fmaf(v.w, wd, acc.w);
    }
    __shared__ float4 red[16][16];
    red[dg][tq] = acc;
    __syncthreads();
    if (tid < 16) {
        float4 s = red[0][tid];
#pragma unroll
        for (int g = 1; g < 16; ++g) {
            float4 r = red[g][tid];
            s.x += r.x; s.y += r.y; s.z += r.z; s.w += r.w;
        }
        int t = t0c + tid * 4;
        float4 o;
        o.x = (t + 0 < xl) ? __expf(s.x) : 0.f;
        o.y = (t + 1 < xl) ? __expf(s.y) : 0.f;
        o.z = (t + 2 < xl) ? __expf(s.z) : 0.f;
        o.w = (t + 3 < xl) ? __expf(s.w) : 0.f;
        *(float4*)&score[b * Tn + t] = o;
    }
}

// ---------------- K2: per-b scan -> norm, loss partial, z_mask, z_len ----
__global__ __launch_bounds__(256) void scan_kernel(const float* __restrict__ score,
                                                   const int* __restrict__ xlen,
                                                   float* __restrict__ norm,
                                                   float* __restrict__ loss_part,
                                                   float* __restrict__ zmask_out,
                                                   float* __restrict__ zlen_out) {
    int b = blockIdx.x, tid = threadIdx.x;
    int xl = xlen[b];
    int zl = (xl + 3) >> 2;
    const float* sc = score + b * Tn;

    float v[8]; float s = 0.f;
#pragma unroll
    for (int k = 0; k < 8; ++k) { v[k] = sc[tid * 8 + k]; s += v[k]; }

    float ps = s;
#pragma unroll
    for (int off = 1; off < 64; off <<= 1) {
        float n = __shfl_up(ps, off, 64);
        if ((tid & 63) >= off) ps += n;
    }
    __shared__ float wsum[4];
    if ((tid & 63) == 63) wsum[tid >> 6] = ps;
    __syncthreads();
    float base = 0.f;
#pragma unroll
    for (int wv = 0; wv < 4; ++wv) if (wv < (tid >> 6)) base += wsum[wv];
    float total = wsum[0] + wsum[1] + wsum[2] + wsum[3];
    float cum0  = sc[0];
    float scale = (float)(zl - 1) / (total - cum0);

    float run = base + ps - s;
#pragma unroll
    for (int k = 0; k < 8; ++k) {
        run += v[k];
        norm[b * Tn + tid * 8 + k] = (run - cum0) * scale;
    }

    float ls = 0.f;
#pragma unroll
    for (int k = 0; k < 8; ++k) {
        int t = tid * 8 + k;
        if (t >= 1 && t < xl) {
            float diff = v[k] * scale;
            ls += fmaxf(diff - 1.0f, 0.f);
        }
    }
#pragma unroll
    for (int off = 32; off; off >>= 1) ls += __shfl_down(ls, off, 64);
    __shared__ float lw[4];
    if ((tid & 63) == 0) lw[tid >> 6] = ls;
    __syncthreads();
    if (tid == 0) loss_part[b] = (lw[0] + lw[1] + lw[2] + lw[3]) / (float)(xl - 1);

    for (int l = tid; l < Ln; l += 256)
        zmask_out[b * Ln + l] = (l * 4 < xl) ? 1.f : 0.f;
    if (tid == 0) zlen_out[b] = (float)zl;
}

// ---------------- K3: alignment[b,l,:] = softmax_t(-5(l-norm)^2) ---------
__global__ __launch_bounds__(256) void softmax_kernel(const float* __restrict__ norm,
                                                      const int* __restrict__ xlen,
                                                      float* __restrict__ align) {
    int bl  = blockIdx.x;
    int b   = bl >> 9;
    int l   = bl & (Ln - 1);
    int tid = threadIdx.x;
    int xl  = xlen[b];
    int zl  = (xl + 3) >> 2;
    float* arow = align + (size_t)bl * Tn;
    if (l >= zl) {
        float4 zz = make_float4(0.f, 0.f, 0.f, 0.f);
        *(float4*)&arow[tid * 8]     = zz;
        *(float4*)&arow[tid * 8 + 4] = zz;
        return;
    }
    const float* nb = norm + b * Tn;
    float dv[8], mx = -1e30f;
#pragma unroll
    for (int k = 0; k < 8; ++k) {
        int t = tid * 8 + k;
        float df = (float)l - nb[t];
        float dd = -kSigmaSq * df * df;
        dv[k] = (t < xl) ? dd : -1e30f;
        mx = fmaxf(mx, dv[k]);
    }
#pragma unroll
    for (int off = 32; off; off >>= 1) mx = fmaxf(mx, __shfl_xor(mx, off, 64));
    __shared__ float sr1[4], sr2[4];
    if ((tid & 63) == 0) sr1[tid >> 6] = mx;
    __syncthreads();
    mx = fmaxf(fmaxf(sr1[0], sr1[1]), fmaxf(sr1[2], sr1[3]));
    float e[8], sum = 0.f;
#pragma unroll
    for (int k = 0; k < 8; ++k) { e[k] = __expf(dv[k] - mx); sum += e[k]; }
#pragma unroll
    for (int off = 32; off; off >>= 1) sum += __shfl_xor(sum, off, 64);
    if ((tid & 63) == 0) sr2[tid >> 6] = sum;
    __syncthreads();
    sum = sr2[0] + sr2[1] + sr2[2] + sr2[3];
    float inv = 1.0f / sum;
    float4 o0 = make_float4(e[0] * inv, e[1] * inv, e[2] * inv, e[3] * inv);
    float4 o1 = make_float4(e[4] * inv, e[5] * inv, e[6] * inv, e[7] * inv);
    *(float4*)&arow[tid * 8]     = o0;
    *(float4*)&arow[tid * 8 + 4] = o1;
}

// ---------------- K4: z[b,d,l] = sum_t align[b,l,t]*x[b,d,t] (windowed) --
__device__ __forceinline__ int lb_ge(const float* a, int n, float v) {
    int lo = 0, hi = n;
    while (lo < hi) { int m = (lo + hi) >> 1; if (a[m] < v) lo = m + 1; else hi = m; }
    return lo;
}
__device__ __forceinline__ int ub_gt(const float* a, int n, float v) {
    int lo = 0, hi = n;
    while (lo < hi) { int m = (lo + hi) >> 1; if (a[m] <= v) lo = m + 1; else hi = m; }
    return lo;
}

#define ZD 128
#define ZL 8
#define ZT 16
#define ZMARGIN 1.5f

// Single-wave blocks. Tile 128d x 8l, TC=16. Lane owns d = d0+tid and
// d0+64+tid, all 8 l. x: float4 loads ALONG t straight to registers (one
// 64B line per row per tile; no LDS, no transpose). A: 512B tile in LDS,
// same-address b128 broadcast reads. Register+LDS ping-pong, no barriers.
__global__ __launch_bounds__(64) void zgemm5_kernel(const float* __restrict__ x,
                                                    const float* __restrict__ align,
                                                    const float* __restrict__ norm,
                                                    const int* __restrict__ xlen,
                                                    const float* __restrict__ loss_part,
                                                    float* __restrict__ z,
                                                    float* __restrict__ out_loss) {
    int tid = threadIdx.x;
    if (blockIdx.x == 0 && tid == 0) {          // fold loss finalize
        float s = 0.f;
        for (int i = 0; i < Bn; ++i) s += loss_part[i];
        out_loss[0] = s / (float)Bn;
    }
    int wg  = blockIdx.x;
    int swz = (wg & 7) * 512 + (wg >> 3);       // bijective XCD swizzle
    int b   = swz >> 8;
    int dq4 = (swz >> 6) & 3;
    int lt  = swz & 63;
    int l0  = lt * ZL, d0 = dq4 * ZD;
    int xl  = xlen[b];
    int zl  = (xl + 3) >> 2;

    size_t zoff0 = (size_t)(b * Dn + d0 + tid) * Ln + l0;
    size_t zoff1 = (size_t)(b * Dn + d0 + 64 + tid) * Ln + l0;

    if (l0 >= zl) {                              // alignment rows are zero
        float4 zz = make_float4(0.f, 0.f, 0.f, 0.f);
        *(float4*)&z[zoff0] = zz; *(float4*)&z[zoff0 + 4] = zz;
        *(float4*)&z[zoff1] = zz; *(float4*)&z[zoff1 + 4] = zz;
        return;
    }

    const float* nb = norm + b * Tn;
    int t_lo = lb_ge(nb, Tn, (float)l0 - ZMARGIN) & ~(ZT - 1);
    int t_hi = ub_gt(nb, Tn, (float)(l0 + ZL - 1) + ZMARGIN);
    if (t_hi > xl) t_hi = xl;
    int ntiles = (t_hi > t_lo) ? ((t_hi - t_lo + ZT - 1) >> 4) : 0;

    __shared__ float sA[2][ZT][ZL];              // 1 KB

    const float* xr0 = x + (size_t)(b * Dn + d0 + tid) * Tn;
    const float* xr1 = x + (size_t)(b * Dn + d0 + 64 + tid) * Tn;
    int at = tid >> 3, al = tid & 7;
    const float* ap = align + (size_t)(b * Ln + l0 + al) * Tn;

    float acc[2][ZL] = {};
    float4 rxA[2][4], rxB[2][4];
    float2 raA, raB;

#define XLOAD(RX, T0)                                                          \
    {                                                                          \
        _Pragma("unroll")                                                      \
        for (int j = 0; j < 4; ++j) {                                          \
            RX[0][j] = *(const float4*)&xr0[(T0) + 4 * j];                     \
            RX[1][j] = *(const float4*)&xr1[(T0) + 4 * j];                     \
        }                                                                      \
    }
#define ALOAD(RA, T0)                                                          \
    {                                                                          \
        int ta = (T0) + at, tb = ta + 8;                                       \
        RA.x = (ta < t_hi) ? ap[ta] : 0.f;                                     \
        RA.y = (tb < t_hi) ? ap[tb] : 0.f;                                     \
    }
#define AWRITE(BUF, RA)                                                        \
    {                                                                          \
        sA[BUF][at][al]     = RA.x;                                            \
        sA[BUF][at + 8][al] = RA.y;                                            \
    }
#define COMPUTE(RX, BUF)                                                       \
    {                                                                          \
        _Pragma("unroll")                                                      \
        for (int t = 0; t < ZT; ++t) {                                         \
            float4 a0 = *(const float4*)&sA[BUF][t][0];                        \
            float4 a1 = *(const float4*)&sA[BUF][t][4];                        \
            float x0 = ((const float*)&RX[0][t >> 2])[t & 3];                  \
            float x1 = ((const float*)&RX[1][t >> 2])[t & 3];                  \
            float aw[8] = {a0.x, a0.y, a0.z, a0.w, a1.x, a1.y, a1.z, a1.w};    \
            _Pragma("unroll")                                                  \
            for (int j = 0; j < 8; ++j) {                                      \
                acc[0][j] = fmaf(x0, aw[j], acc[0][j]);                        \
                acc[1][j] = fmaf(x1, aw[j], acc[1][j]);                        \
            }                                                                  \
        }                                                                      \
    }

    if (ntiles > 0) {
        XLOAD(rxA, t_lo); ALOAD(raA, t_lo); AWRITE(0, raA);
    }
    for (int it = 0; it < ntiles; it += 2) {
        if (it + 1 < ntiles) { XLOAD(rxB, t_lo + (it + 1) * ZT); ALOAD(raB, t_lo + (it + 1) * ZT); }
        COMPUTE(rxA, 0);
        if (it + 1 < ntiles) AWRITE(1, raB);
        if (it + 2 < ntiles) { XLOAD(rxA, t_lo + (it + 2) * ZT); ALOAD(raA, t_lo + (it + 2) * ZT); }
        if (it + 1 < ntiles) COMPUTE(rxB, 1);
        if (it + 2 < ntiles) AWRITE(0, raA);
    }

    float4 o00 = make_float4(acc[0][0], acc[0][1], acc[0][2], acc[0][3]);
    float4 o01 = make_float4(acc[0][4], acc[0][5], acc[0][6], acc[0][7]);
    float4 o10 = make_float4(acc[1][0], acc[1][1], acc[1][2], acc[1][3]);
    float4 o11 = make_float4(acc[1][4], acc[1][5], acc[1][6], acc[1][7]);
    *(float4*)&z[zoff0]     = o00;
    *(float4*)&z[zoff0 + 4] = o01;
    *(float4*)&z[zoff1]     = o10;
    *(float4*)&z[zoff1 + 4] = o11;
#undef XLOAD
#undef ALOAD
#undef AWRITE
#undef COMPUTE
}

extern "C" void kernel_launch(void* const* d_in, const int* in_sizes, int n_in,
                              void* d_out, int out_size, void* d_ws, size_t ws_size,
                              hipStream_t stream) {
    const float* x    = (const float*)d_in[0];
    const float* w    = (const float*)d_in[1];
    const int*   xlen = (const int*)d_in[3];
    float* out = (float*)d_out;

    const size_t OFF_Z     = 0;
    const size_t OFF_ZMASK = (size_t)Bn * Dn * Ln;
    const size_t OFF_ZLEN  = OFF_ZMASK + (size_t)Bn * Ln;
    const size_t OFF_ALIGN = OFF_ZLEN + Bn;
    const size_t OFF_LOSS  = OFF_ALIGN + (size_t)Bn * Ln * Tn;

    float* score     = (float*)d_ws;
    float* norm      = score + (size_t)Bn * Tn;
    float* loss_part = norm + (size_t)Bn * Tn;

    score_kernel<<<Bn * 32, 256, 0, stream>>>(x, w, xlen, score);
    scan_kernel<<<Bn, 256, 0, stream>>>(score, xlen, norm, loss_part,
                                        out + OFF_ZMASK, out + OFF_ZLEN);
    softmax_kernel<<<Bn * Ln, 256, 0, stream>>>(norm, xlen, out + OFF_ALIGN);
    zgemm5_kernel<<<Bn * 4 * 64, 64, 0, stream>>>(x, out + OFF_ALIGN, norm, xlen,
                                                  loss_part, out + OFF_Z, out + OFF_LOSS);
}